// Round 4
// baseline (2397.527 us; speedup 1.0000x reference)
//
#include <hip/hip_runtime.h>
#include <math.h>

// ---------------------------------------------------------------------------
// Swin block on MI355X — split-precision bf16 MFMA GEMMs (hi/lo bf16x3 ≈ fp32
// accuracy), fused window attention in fp32. Chunked over 4 window groups to
// cap workspace at ~448 MB (qkv and MLP-hidden never fully resident).
// B=32 H=W=56 C=384 WIN=7 SHIFT=3 HEADS=12 HD=32 MLP=1536
// bf16 carried as raw u16 bits (no __bf16 dependency).
// ---------------------------------------------------------------------------

typedef unsigned short u16;
typedef short s16x8 __attribute__((ext_vector_type(8)));   // 8 bf16 (4 VGPRs)
typedef float f32x4 __attribute__((ext_vector_type(4)));

constexpr int TOKENS  = 100352;
constexpr int CDIM    = 384;
constexpr int QKVDIM  = 1152;
constexpr int MLPDIM  = 1536;
constexpr int NWIN    = 2048;
constexpr int NCHUNK  = 4;
constexpr int WCHUNK  = NWIN / NCHUNK;          // 512 windows
constexpr int MCHUNK  = WCHUNK * 49;            // 25088 rows = 196*128
constexpr float SCALE = 0.17677669529663688f;   // 32^-0.5

__device__ __forceinline__ int win_to_token(int r) {
    int wi = r / 49;
    int n  = r - wi * 49;
    int b  = wi >> 6;
    int nw = wi & 63;
    int i  = n / 7;
    int j  = n - i * 7;
    int h  = (nw >> 3) * 7 + i + 3; if (h >= 56) h -= 56;
    int w  = (nw & 7) * 7 + j + 3;  if (w >= 56) w -= 56;
    return (b * 56 + h) * 56 + w;
}

__device__ __forceinline__ float gelu_f(float x) {
    return 0.5f * x * (1.0f + erff(x * 0.70710678118654752f));
}

__device__ __forceinline__ f32x4 mfma16(s16x8 a, s16x8 b, f32x4 c) {
    return __builtin_amdgcn_mfma_f32_16x16x32_bf16(a, b, c, 0, 0, 0);
}

__device__ __forceinline__ u16 f2bf(float f) {           // RTNE
    unsigned u = __float_as_uint(f);
    u += 0x7FFFu + ((u >> 16) & 1u);
    return (u16)(u >> 16);
}
__device__ __forceinline__ float bf2f(u16 h) {
    return __uint_as_float((unsigned)h << 16);
}
__device__ __forceinline__ void split_store(float v, u16* ph, u16* pl) {
    u16 h = f2bf(v);
    *ph = h;
    *pl = f2bf(v - bf2f(h));   // v-hi exact (Sterbenz); residual ~2^-18|v|
}

// ---------------------------------------------------------------------------
// LayerNorm over C=384, hi/lo bf16 output. One wave per row, 4 rows/block.
// GATHER=1: row r reads token win_to_token(r)  (window-order output)
// ---------------------------------------------------------------------------
template <int GATHER>
__global__ __launch_bounds__(256) void ln_k(const float* __restrict__ in,
                                            const float* __restrict__ gam,
                                            const float* __restrict__ bet,
                                            u16* __restrict__ oh,
                                            u16* __restrict__ ol) {
    int r    = blockIdx.x * 4 + (threadIdx.x >> 6);
    int lane = threadIdx.x & 63;
    int src  = GATHER ? win_to_token(r) : r;
    const float* xr = in + (size_t)src * CDIM;
    float v[6];
    float s = 0.f, s2 = 0.f;
#pragma unroll
    for (int p = 0; p < 6; ++p) {
        float t = xr[lane + 64 * p];
        v[p] = t; s += t; s2 += t * t;
    }
#pragma unroll
    for (int off = 32; off; off >>= 1) {
        s  += __shfl_xor(s, off);
        s2 += __shfl_xor(s2, off);
    }
    float mean = s * (1.f / 384.f);
    float var  = s2 * (1.f / 384.f) - mean * mean;
    float rstd = rsqrtf(var + 1e-5f);
    size_t rb = (size_t)r * CDIM;
#pragma unroll
    for (int p = 0; p < 6; ++p) {
        int c = lane + 64 * p;
        float y = (v[p] - mean) * rstd * gam[c] + bet[c];
        split_store(y, oh + rb + c, ol + rb + c);
    }
}

// ---------------------------------------------------------------------------
// Weight transpose + hi/lo split: W[K][N] fp32 -> Th/Tl[N][K] bf16-bits
// ---------------------------------------------------------------------------
__global__ __launch_bounds__(256) void wsplit_k(const float* __restrict__ W,
                                                u16* __restrict__ Th,
                                                u16* __restrict__ Tl,
                                                int K, int N) {
    __shared__ float t[32][33];
    int k0 = blockIdx.x * 32, n0 = blockIdx.y * 32;
    int tx = threadIdx.x & 31, ty = threadIdx.x >> 5;  // ty 0..7
#pragma unroll
    for (int i = 0; i < 4; ++i)
        t[ty + 8 * i][tx] = W[(size_t)(k0 + ty + 8 * i) * N + n0 + tx];
    __syncthreads();
#pragma unroll
    for (int i = 0; i < 4; ++i) {
        int n = n0 + ty + 8 * i, k = k0 + tx;
        split_store(t[tx][ty + 8 * i],
                    Th + (size_t)n * K + k, Tl + (size_t)n * K + k);
    }
}

// ---------------------------------------------------------------------------
// Split-precision bf16 MFMA GEMM.
//   C[M,N] = (Ah+Al)[M,K] @ (Bh+Bl)^T[N,K]  (3 terms: hh + hl + lh)
// 128x128 tile, BK=32, 4 waves (2x2), per-wave 64x64 = 4x4 16x16x32 frags.
// LDS: per plane [128 rows][32 k] bf16 = 64 B/row; XOR slot swizzle
//   phys_slot = (logical_chunk + (row>>1)) & 3  -> 2-way bank access (free)
// MODE 0: +bias -> fp32        MODE 1: +bias, scatter row (+wbase), +skip
// MODE 2: gelu(+bias) -> hi/lo MODE 3: +bias +skip -> fp32 (skip may == C)
// ---------------------------------------------------------------------------
template <int MODE>
__global__ __launch_bounds__(256, 2) void bgemm_k(
    const u16* __restrict__ Ah, const u16* __restrict__ Al,
    const u16* __restrict__ Bh, const u16* __restrict__ Bl,
    const float* __restrict__ bias, const float* __restrict__ skip,
    float* __restrict__ Cf, u16* __restrict__ Ch, u16* __restrict__ Cl,
    int N, int K) {
    __shared__ u16 sAh[128 * 32], sAl[128 * 32];
    __shared__ u16 sBh[128 * 32], sBl[128 * 32];

    const int tid  = threadIdx.x;
    const int lane = tid & 63;
    const int w    = tid >> 6;
    const int wm   = w >> 1, wn = w & 1;
    const int m0   = blockIdx.x * 128, n0 = blockIdx.y * 128;

    // ---- staging geometry (256 thr x 16 B x 2 passes per 8 KB plane) ----
    const int srow = tid >> 2;                    // 0..63 (+64 pass 1)
    const int sl   = tid & 3;                     // logical 16B k-chunk
    const int sp   = (sl + ((tid >> 3) & 3)) & 3; // physical slot (row>>1 mix)
    const int ldsb = srow * 64 + sp * 16;         // byte offset, pass 0
    const size_t gA = (size_t)(m0 + srow) * K + sl * 8;
    const size_t gB = (size_t)(n0 + srow) * K + sl * 8;
    const size_t rowskip = (size_t)64 * K;

    // ---- fragment-read geometry ----
    const int fr = lane & 15;                     // M/N index within frag
    const int fg = lane >> 4;                     // logical k-chunk
    const int fp = (((fr >> 1) & 3) + fg) & 3;    // physical slot
    const int aoffb = (wm * 64 + fr) * 64 + fp * 16;  // + mi*1024
    const int boffb = (wn * 64 + fr) * 64 + fp * 16;  // + ni*1024

    f32x4 acc[4][4] = {};

    s16x8 pah0 = *(const s16x8*)(Ah + gA);
    s16x8 pah1 = *(const s16x8*)(Ah + gA + rowskip);
    s16x8 pal0 = *(const s16x8*)(Al + gA);
    s16x8 pal1 = *(const s16x8*)(Al + gA + rowskip);
    s16x8 pbh0 = *(const s16x8*)(Bh + gB);
    s16x8 pbh1 = *(const s16x8*)(Bh + gB + rowskip);
    s16x8 pbl0 = *(const s16x8*)(Bl + gB);
    s16x8 pbl1 = *(const s16x8*)(Bl + gB + rowskip);

    for (int k0 = 0; k0 < K; k0 += 32) {
        __syncthreads();   // prior iteration's frag reads complete
        *(s16x8*)((char*)sAh + ldsb)        = pah0;
        *(s16x8*)((char*)sAh + ldsb + 4096) = pah1;
        *(s16x8*)((char*)sAl + ldsb)        = pal0;
        *(s16x8*)((char*)sAl + ldsb + 4096) = pal1;
        *(s16x8*)((char*)sBh + ldsb)        = pbh0;
        *(s16x8*)((char*)sBh + ldsb + 4096) = pbh1;
        *(s16x8*)((char*)sBl + ldsb)        = pbl0;
        *(s16x8*)((char*)sBl + ldsb + 4096) = pbl1;
        __syncthreads();

        if (k0 + 32 < K) {  // prefetch next K-tile (hides under MFMAs)
            const size_t a = gA + k0 + 32, b = gB + k0 + 32;
            pah0 = *(const s16x8*)(Ah + a);
            pah1 = *(const s16x8*)(Ah + a + rowskip);
            pal0 = *(const s16x8*)(Al + a);
            pal1 = *(const s16x8*)(Al + a + rowskip);
            pbh0 = *(const s16x8*)(Bh + b);
            pbh1 = *(const s16x8*)(Bh + b + rowskip);
            pbl0 = *(const s16x8*)(Bl + b);
            pbl1 = *(const s16x8*)(Bl + b + rowskip);
        }

        s16x8 aH[4], aL[4], bH[4], bL[4];
#pragma unroll
        for (int i = 0; i < 4; ++i) {
            aH[i] = *(const s16x8*)((char*)sAh + aoffb + i * 1024);
            aL[i] = *(const s16x8*)((char*)sAl + aoffb + i * 1024);
            bH[i] = *(const s16x8*)((char*)sBh + boffb + i * 1024);
            bL[i] = *(const s16x8*)((char*)sBl + boffb + i * 1024);
        }
#pragma unroll
        for (int mi = 0; mi < 4; ++mi)
#pragma unroll
            for (int ni = 0; ni < 4; ++ni) {
                acc[mi][ni] = mfma16(aH[mi], bH[ni], acc[mi][ni]);
                acc[mi][ni] = mfma16(aH[mi], bL[ni], acc[mi][ni]);
                acc[mi][ni] = mfma16(aL[mi], bH[ni], acc[mi][ni]);
            }
    }

    // ---- epilogue: D elem j of lane = C[row=(lane>>4)*4+j][col=lane&15] ----
#pragma unroll
    for (int mi = 0; mi < 4; ++mi)
#pragma unroll
        for (int ni = 0; ni < 4; ++ni) {
            const f32x4 a  = acc[mi][ni];
            const int col  = n0 + wn * 64 + ni * 16 + fr;
            const float bv = bias[col];
#pragma unroll
            for (int j = 0; j < 4; ++j) {
                const int row = m0 + wm * 64 + mi * 16 + fg * 4 + j;
                float v = a[j] + bv;
                if (MODE == 0) {
                    Cf[(size_t)row * N + col] = v;
                } else if (MODE == 1) {
                    const int tr = win_to_token(row);
                    v += skip[(size_t)tr * N + col];
                    Cf[(size_t)tr * N + col] = v;
                } else if (MODE == 2) {
                    v = gelu_f(v);
                    split_store(v, Ch + (size_t)row * N + col,
                                   Cl + (size_t)row * N + col);
                } else {
                    v += skip[(size_t)row * N + col];  // skip may alias Cf:
                    Cf[(size_t)row * N + col] = v;     // same-thread RMW, safe
                }
            }
        }
}

// ---------------------------------------------------------------------------
// Fused window attention (fp32): one block per (window, head).
// qkv is CHUNK-LOCAL: row [wl*49+n][s*384 + head*32 + d], wl = local window.
// wbase: global window id of chunk start (for mask + output indexing).
// out -> full-size hi/lo bf16 planes in window order.
// ---------------------------------------------------------------------------
__device__ __forceinline__ int regof(int p) {
    return p < 49 ? 0 : (p < 53 ? 1 : 2);
}

__global__ __launch_bounds__(256) void attn_k(const float* __restrict__ qkv,
                                              const float* __restrict__ rpb,
                                              u16* __restrict__ oh,
                                              u16* __restrict__ ol,
                                              int wbase) {
    const int wl   = blockIdx.x;           // local window in chunk
    const int wi   = wbase + wl;           // global window
    const int head = blockIdx.y;
    __shared__ float qs[49][33], ks[49][33], vs[49][33];
    __shared__ float S[49][52];

    const float* basep = qkv + (size_t)wl * 49 * QKVDIM + head * 32;
    for (int idx = threadIdx.x; idx < 49 * 32; idx += 256) {
        int n = idx >> 5, d = idx & 31;
        qs[n][d] = basep[n * QKVDIM + d] * SCALE;
        ks[n][d] = basep[n * QKVDIM + 384 + d];
        vs[n][d] = basep[n * QKVDIM + 768 + d];
    }
    __syncthreads();

    const int nw = wi & 63;
    const int wh = nw >> 3, ww = nw & 7;

    for (int idx = threadIdx.x; idx < 49 * 49; idx += 256) {
        int n = idx / 49, m = idx - n * 49;
        float s = 0.f;
#pragma unroll
        for (int d = 0; d < 32; ++d) s += qs[n][d] * ks[m][d];
        int i1 = n / 7, j1 = n - i1 * 7;
        int i2 = m / 7, j2 = m - i2 * 7;
        s += rpb[((i1 - i2 + 6) * 13 + (j1 - j2 + 6)) * 12 + head];
        int r1 = regof(wh * 7 + i1) * 3 + regof(ww * 7 + j1);
        int r2 = regof(wh * 7 + i2) * 3 + regof(ww * 7 + j2);
        if (r1 != r2) s -= 100.0f;
        S[n][m] = s;
    }
    __syncthreads();

    const int wave = threadIdx.x >> 6, lane = threadIdx.x & 63;
    for (int n = wave; n < 49; n += 4) {
        float s = (lane < 49) ? S[n][lane] : -1e30f;
        float mx = s;
#pragma unroll
        for (int off = 32; off; off >>= 1) mx = fmaxf(mx, __shfl_xor(mx, off));
        float e = (lane < 49) ? expf(s - mx) : 0.f;
        float sum = e;
#pragma unroll
        for (int off = 32; off; off >>= 1) sum += __shfl_xor(sum, off);
        if (lane < 49) S[n][lane] = e / sum;
    }
    __syncthreads();

    for (int idx = threadIdx.x; idx < 49 * 32; idx += 256) {
        int n = idx >> 5, d = idx & 31;
        float o = 0.f;
        for (int m = 0; m < 49; ++m) o += S[n][m] * vs[m][d];
        size_t oidx = ((size_t)wi * 49 + n) * CDIM + head * 32 + d;
        split_store(o, oh + oidx, ol + oidx);
    }
}

// ---------------------------------------------------------------------------
// Launcher.  Workspace (bytes):
//   [0,154M)    xnh/xnl           u16, window order, live LN1->qkv & LN2->mlp1
//   [154M,308M) scratch: qkv f32 chunk (116M) OR mlp hidden hi/lo chunk (154M)
//   [308M,462M) aoh/aol           u16, window order
//   [462M,469M) weight planes     u16
// Total ~448 MB.  x2 (post-attn residual) lives in d_out; mlp2 does the
// in-place skip+write (same-thread RMW).
// ---------------------------------------------------------------------------
extern "C" void kernel_launch(void* const* d_in, const int* in_sizes, int n_in,
                              void* d_out, int out_size, void* d_ws,
                              size_t ws_size, hipStream_t stream) {
    (void)in_sizes; (void)n_in; (void)out_size; (void)ws_size;
    const float* x      = (const float*)d_in[0];
    const float* n1g    = (const float*)d_in[1];
    const float* n1b    = (const float*)d_in[2];
    const float* qkv_w  = (const float*)d_in[3];
    const float* qkv_b  = (const float*)d_in[4];
    const float* proj_w = (const float*)d_in[5];
    const float* proj_b = (const float*)d_in[6];
    const float* rpb    = (const float*)d_in[7];
    const float* n2g    = (const float*)d_in[8];
    const float* n2b    = (const float*)d_in[9];
    const float* w1     = (const float*)d_in[10];
    const float* b1     = (const float*)d_in[11];
    const float* w2     = (const float*)d_in[12];
    const float* b2     = (const float*)d_in[13];

    const size_t R384 = (size_t)TOKENS * CDIM;      // 38,535,168

    u16*   xnh  = (u16*)d_ws;                       // [TOKENS*384]
    u16*   xnl  = xnh + R384;
    char*  scr  = (char*)(xnl + R384);              // 154,140,672 B scratch
    float* qkvc = (float*)scr;                      // [MCHUNK*1152] f32
    u16*   hh   = (u16*)scr;                        // [MCHUNK*1536] hi
    u16*   hl   = hh + (size_t)MCHUNK * MLPDIM;     // [MCHUNK*1536] lo
    u16*   aoh  = (u16*)(scr + (size_t)2 * MCHUNK * MLPDIM * sizeof(u16));
    u16*   aol  = aoh + R384;
    u16*   wqh  = aol + R384;                       // weight planes (~7 MB)
    u16*   wql  = wqh + (size_t)CDIM * QKVDIM;
    u16*   wph  = wql + (size_t)CDIM * QKVDIM;
    u16*   wpl  = wph + (size_t)CDIM * CDIM;
    u16*   w1h  = wpl + (size_t)CDIM * CDIM;
    u16*   w1l  = w1h + (size_t)CDIM * MLPDIM;
    u16*   w2h  = w1l + (size_t)CDIM * MLPDIM;
    u16*   w2l  = w2h + (size_t)MLPDIM * CDIM;
    float* x2   = (float*)d_out;                    // post-attn residual

    // weight transpose + split (every call; ws re-poisoned by harness)
    wsplit_k<<<dim3(CDIM / 32, QKVDIM / 32), 256, 0, stream>>>(qkv_w, wqh, wql, CDIM, QKVDIM);
    wsplit_k<<<dim3(CDIM / 32, CDIM / 32), 256, 0, stream>>>(proj_w, wph, wpl, CDIM, CDIM);
    wsplit_k<<<dim3(CDIM / 32, MLPDIM / 32), 256, 0, stream>>>(w1, w1h, w1l, CDIM, MLPDIM);
    wsplit_k<<<dim3(MLPDIM / 32, CDIM / 32), 256, 0, stream>>>(w2, w2h, w2l, MLPDIM, CDIM);

    // LN1 (token->window gather) over all tokens
    ln_k<1><<<TOKENS / 4, 256, 0, stream>>>(x, n1g, n1b, xnh, xnl);

    // qkv GEMM + attention, chunked (qkv never fully resident)
    for (int c = 0; c < NCHUNK; ++c) {
        const size_t ro = (size_t)c * MCHUNK;
        bgemm_k<0><<<dim3(MCHUNK / 128, QKVDIM / 128), 256, 0, stream>>>(
            xnh + ro * CDIM, xnl + ro * CDIM, wqh, wql, qkv_b, nullptr,
            qkvc, nullptr, nullptr, QKVDIM, CDIM);
        attn_k<<<dim3(WCHUNK, 12), 256, 0, stream>>>(
            qkvc, rpb, aoh, aol, c * WCHUNK);
    }

    // proj GEMM: window order -> token order scatter, +skip(x), into d_out
    bgemm_k<1><<<dim3(TOKENS / 128, CDIM / 128), 256, 0, stream>>>(
        aoh, aol, wph, wpl, proj_b, x, x2, nullptr, nullptr, CDIM, CDIM);

    // LN2 (token order, in-place source d_out)
    ln_k<0><<<TOKENS / 4, 256, 0, stream>>>(x2, n2g, n2b, xnh, xnl);

    // MLP, chunked (hidden never fully resident); mlp2 in-place on d_out
    for (int c = 0; c < NCHUNK; ++c) {
        const size_t ro = (size_t)c * MCHUNK;
        bgemm_k<2><<<dim3(MCHUNK / 128, MLPDIM / 128), 256, 0, stream>>>(
            xnh + ro * CDIM, xnl + ro * CDIM, w1h, w1l, b1, nullptr,
            nullptr, hh, hl, MLPDIM, CDIM);
        bgemm_k<3><<<dim3(MCHUNK / 128, CDIM / 128), 256, 0, stream>>>(
            hh, hl, w2h, w2l, b2, x2 + ro * CDIM, x2 + ro * CDIM,
            nullptr, nullptr, CDIM, MLPDIM);
    }
}

// Round 5
// 1575.888 us; speedup vs baseline: 1.5214x; 1.5214x over previous
//
#include <hip/hip_runtime.h>
#include <math.h>

// ---------------------------------------------------------------------------
// Swin block on MI355X — single-term fp16 MFMA GEMMs (fp32 accumulate),
// fused window attention in fp32, fp16 activations. Chunked over 4 window
// groups; workspace ~235 MB.
// B=32 H=W=56 C=384 WIN=7 SHIFT=3 HEADS=12 HD=32 MLP=1536
// ---------------------------------------------------------------------------

typedef _Float16 f16;
typedef _Float16 f16x8 __attribute__((ext_vector_type(8)));  // 16 B, 4 VGPRs
typedef float f32x4 __attribute__((ext_vector_type(4)));

constexpr int TOKENS  = 100352;
constexpr int CDIM    = 384;
constexpr int QKVDIM  = 1152;
constexpr int MLPDIM  = 1536;
constexpr int NWIN    = 2048;
constexpr int NCHUNK  = 4;
constexpr int WCHUNK  = NWIN / NCHUNK;          // 512 windows
constexpr int MCHUNK  = WCHUNK * 49;            // 25088 rows = 196*128
constexpr float SCALE = 0.17677669529663688f;   // 32^-0.5

__device__ __forceinline__ int win_to_token(int r) {
    int wi = r / 49;
    int n  = r - wi * 49;
    int b  = wi >> 6;
    int nw = wi & 63;
    int i  = n / 7;
    int j  = n - i * 7;
    int h  = (nw >> 3) * 7 + i + 3; if (h >= 56) h -= 56;
    int w  = (nw & 7) * 7 + j + 3;  if (w >= 56) w -= 56;
    return (b * 56 + h) * 56 + w;
}

__device__ __forceinline__ float gelu_f(float x) {
    return 0.5f * x * (1.0f + erff(x * 0.70710678118654752f));
}

__device__ __forceinline__ f32x4 mfma16(f16x8 a, f16x8 b, f32x4 c) {
    return __builtin_amdgcn_mfma_f32_16x16x32_f16(a, b, c, 0, 0, 0);
}

// ---------------------------------------------------------------------------
// LayerNorm over C=384, fp16 output. One wave per row, 4 rows per block.
// GATHER=1: row r reads token win_to_token(r)  (window-order output)
// ---------------------------------------------------------------------------
template <int GATHER>
__global__ __launch_bounds__(256) void ln_k(const float* __restrict__ in,
                                            const float* __restrict__ gam,
                                            const float* __restrict__ bet,
                                            f16* __restrict__ out) {
    int r    = blockIdx.x * 4 + (threadIdx.x >> 6);
    int lane = threadIdx.x & 63;
    int src  = GATHER ? win_to_token(r) : r;
    const float* xr = in + (size_t)src * CDIM;
    float v[6];
    float s = 0.f, s2 = 0.f;
#pragma unroll
    for (int p = 0; p < 6; ++p) {
        float t = xr[lane + 64 * p];
        v[p] = t; s += t; s2 += t * t;
    }
#pragma unroll
    for (int off = 32; off; off >>= 1) {
        s  += __shfl_xor(s, off);
        s2 += __shfl_xor(s2, off);
    }
    float mean = s * (1.f / 384.f);
    float var  = s2 * (1.f / 384.f) - mean * mean;
    float rstd = rsqrtf(var + 1e-5f);
    size_t rb = (size_t)r * CDIM;
#pragma unroll
    for (int p = 0; p < 6; ++p) {
        int c = lane + 64 * p;
        out[rb + c] = (f16)((v[p] - mean) * rstd * gam[c] + bet[c]);
    }
}

// ---------------------------------------------------------------------------
// Weight transpose + fp16 convert: W[K][N] fp32 -> T[N][K] fp16
// ---------------------------------------------------------------------------
__global__ __launch_bounds__(256) void wsplit_k(const float* __restrict__ W,
                                                f16* __restrict__ T,
                                                int K, int N) {
    __shared__ float t[32][33];
    int k0 = blockIdx.x * 32, n0 = blockIdx.y * 32;
    int tx = threadIdx.x & 31, ty = threadIdx.x >> 5;  // ty 0..7
#pragma unroll
    for (int i = 0; i < 4; ++i)
        t[ty + 8 * i][tx] = W[(size_t)(k0 + ty + 8 * i) * N + n0 + tx];
    __syncthreads();
#pragma unroll
    for (int i = 0; i < 4; ++i) {
        int n = n0 + ty + 8 * i, k = k0 + tx;
        T[(size_t)n * K + k] = (f16)t[tx][ty + 8 * i];
    }
}

// ---------------------------------------------------------------------------
// fp16 MFMA GEMM: C[M,N] = A[M,K] @ B^T[N,K]  (fp32 accumulate)
// 128x128 tile, BK=32, 4 waves (2x2), per-wave 64x64 = 4x4 16x16x32 frags.
// LDS: per plane [128 rows][32 k] f16 = 64 B/row; XOR slot swizzle
//   phys_slot = (logical_chunk + (row>>1)) & 3  -> 2-way bank access (free)
// MODE 0: +bias -> f16         MODE 1: +bias, scatter row, +skip -> fp32
// MODE 2: gelu(+bias) -> f16   MODE 3: +bias +skip -> fp32 (skip may == C)
// ---------------------------------------------------------------------------
template <int MODE>
__global__ __launch_bounds__(256, 2) void bgemm_k(
    const f16* __restrict__ A, const f16* __restrict__ B,
    const float* __restrict__ bias, const float* __restrict__ skip,
    float* __restrict__ Cf, f16* __restrict__ Ch, int N, int K) {
    __shared__ f16 sA[128 * 32];
    __shared__ f16 sB[128 * 32];

    const int tid  = threadIdx.x;
    const int lane = tid & 63;
    const int w    = tid >> 6;
    const int wm   = w >> 1, wn = w & 1;
    const int m0   = blockIdx.x * 128, n0 = blockIdx.y * 128;

    // ---- staging geometry (256 thr x 16 B x 2 passes per 8 KB plane) ----
    const int srow = tid >> 2;                    // 0..63 (+64 pass 1)
    const int sl   = tid & 3;                     // logical 16B k-chunk
    const int sp   = (sl + ((tid >> 3) & 3)) & 3; // physical slot (row>>1 mix)
    const int ldsb = srow * 64 + sp * 16;         // byte offset, pass 0
    const size_t gA = (size_t)(m0 + srow) * K + sl * 8;
    const size_t gB = (size_t)(n0 + srow) * K + sl * 8;
    const size_t rowskip = (size_t)64 * K;

    // ---- fragment-read geometry ----
    const int fr = lane & 15;                     // M/N index within frag
    const int fg = lane >> 4;                     // logical k-chunk
    const int fp = (((fr >> 1) & 3) + fg) & 3;    // physical slot
    const int aoffb = (wm * 64 + fr) * 64 + fp * 16;  // + mi*1024
    const int boffb = (wn * 64 + fr) * 64 + fp * 16;  // + ni*1024

    f32x4 acc[4][4] = {};

    f16x8 pa0 = *(const f16x8*)(A + gA);
    f16x8 pa1 = *(const f16x8*)(A + gA + rowskip);
    f16x8 pb0 = *(const f16x8*)(B + gB);
    f16x8 pb1 = *(const f16x8*)(B + gB + rowskip);

    for (int k0 = 0; k0 < K; k0 += 32) {
        __syncthreads();   // prior iteration's frag reads complete
        *(f16x8*)((char*)sA + ldsb)        = pa0;
        *(f16x8*)((char*)sA + ldsb + 4096) = pa1;
        *(f16x8*)((char*)sB + ldsb)        = pb0;
        *(f16x8*)((char*)sB + ldsb + 4096) = pb1;
        __syncthreads();

        if (k0 + 32 < K) {  // prefetch next K-tile (hides under MFMAs)
            const size_t a = gA + k0 + 32, b = gB + k0 + 32;
            pa0 = *(const f16x8*)(A + a);
            pa1 = *(const f16x8*)(A + a + rowskip);
            pb0 = *(const f16x8*)(B + b);
            pb1 = *(const f16x8*)(B + b + rowskip);
        }

        f16x8 aH[4], bH[4];
#pragma unroll
        for (int i = 0; i < 4; ++i) {
            aH[i] = *(const f16x8*)((char*)sA + aoffb + i * 1024);
            bH[i] = *(const f16x8*)((char*)sB + boffb + i * 1024);
        }
#pragma unroll
        for (int mi = 0; mi < 4; ++mi)
#pragma unroll
            for (int ni = 0; ni < 4; ++ni)
                acc[mi][ni] = mfma16(aH[mi], bH[ni], acc[mi][ni]);
    }

    // ---- epilogue: D elem j of lane = C[row=(lane>>4)*4+j][col=lane&15] ----
#pragma unroll
    for (int mi = 0; mi < 4; ++mi)
#pragma unroll
        for (int ni = 0; ni < 4; ++ni) {
            const f32x4 a  = acc[mi][ni];
            const int col  = n0 + wn * 64 + ni * 16 + fr;
            const float bv = bias[col];
#pragma unroll
            for (int j = 0; j < 4; ++j) {
                const int row = m0 + wm * 64 + mi * 16 + fg * 4 + j;
                float v = a[j] + bv;
                if (MODE == 0) {
                    Ch[(size_t)row * N + col] = (f16)v;
                } else if (MODE == 1) {
                    const int tr = win_to_token(row);
                    v += skip[(size_t)tr * N + col];
                    Cf[(size_t)tr * N + col] = v;
                } else if (MODE == 2) {
                    Ch[(size_t)row * N + col] = (f16)gelu_f(v);
                } else {
                    v += skip[(size_t)row * N + col];  // skip may alias Cf:
                    Cf[(size_t)row * N + col] = v;     // same-thread RMW, safe
                }
            }
        }
}

// ---------------------------------------------------------------------------
// Fused window attention (fp32 internals, fp16 I/O): block per (window,head).
// qkv is CHUNK-LOCAL: row [wl*49+n][s*384 + head*32 + d].
// ---------------------------------------------------------------------------
__device__ __forceinline__ int regof(int p) {
    return p < 49 ? 0 : (p < 53 ? 1 : 2);
}

__global__ __launch_bounds__(256) void attn_k(const f16* __restrict__ qkv,
                                              const float* __restrict__ rpb,
                                              f16* __restrict__ out,
                                              int wbase) {
    const int wl   = blockIdx.x;           // local window in chunk
    const int wi   = wbase + wl;           // global window
    const int head = blockIdx.y;
    __shared__ float qs[49][33], ks[49][33], vs[49][33];
    __shared__ float S[49][52];

    const f16* basep = qkv + (size_t)wl * 49 * QKVDIM + head * 32;
    for (int idx = threadIdx.x; idx < 49 * 32; idx += 256) {
        int n = idx >> 5, d = idx & 31;
        qs[n][d] = (float)basep[n * QKVDIM + d] * SCALE;
        ks[n][d] = (float)basep[n * QKVDIM + 384 + d];
        vs[n][d] = (float)basep[n * QKVDIM + 768 + d];
    }
    __syncthreads();

    const int nw = wi & 63;
    const int wh = nw >> 3, ww = nw & 7;

    for (int idx = threadIdx.x; idx < 49 * 49; idx += 256) {
        int n = idx / 49, m = idx - n * 49;
        float s = 0.f;
#pragma unroll
        for (int d = 0; d < 32; ++d) s += qs[n][d] * ks[m][d];
        int i1 = n / 7, j1 = n - i1 * 7;
        int i2 = m / 7, j2 = m - i2 * 7;
        s += rpb[((i1 - i2 + 6) * 13 + (j1 - j2 + 6)) * 12 + head];
        int r1 = regof(wh * 7 + i1) * 3 + regof(ww * 7 + j1);
        int r2 = regof(wh * 7 + i2) * 3 + regof(ww * 7 + j2);
        if (r1 != r2) s -= 100.0f;
        S[n][m] = s;
    }
    __syncthreads();

    const int wave = threadIdx.x >> 6, lane = threadIdx.x & 63;
    for (int n = wave; n < 49; n += 4) {
        float s = (lane < 49) ? S[n][lane] : -1e30f;
        float mx = s;
#pragma unroll
        for (int off = 32; off; off >>= 1) mx = fmaxf(mx, __shfl_xor(mx, off));
        float e = (lane < 49) ? expf(s - mx) : 0.f;
        float sum = e;
#pragma unroll
        for (int off = 32; off; off >>= 1) sum += __shfl_xor(sum, off);
        if (lane < 49) S[n][lane] = e / sum;
    }
    __syncthreads();

    for (int idx = threadIdx.x; idx < 49 * 32; idx += 256) {
        int n = idx >> 5, d = idx & 31;
        float o = 0.f;
        for (int m = 0; m < 49; ++m) o += S[n][m] * vs[m][d];
        out[((size_t)wi * 49 + n) * CDIM + head * 32 + d] = (f16)o;
    }
}

// ---------------------------------------------------------------------------
// Launcher.  Workspace (f16 elements):  total ~235 MB
//   xn   [TOKENS*384]    LN out, window order (LN1) / token order (LN2)
//   scr  [MCHUNK*1536]   chunk scratch: qkv f16 chunk OR mlp hidden chunk
//   ao   [TOKENS*384]    attn out, window order
//   weights ~1.8M elems
// x2 (post-attn residual, fp32) lives in d_out; mlp2 skip+write in place.
// ---------------------------------------------------------------------------
extern "C" void kernel_launch(void* const* d_in, const int* in_sizes, int n_in,
                              void* d_out, int out_size, void* d_ws,
                              size_t ws_size, hipStream_t stream) {
    (void)in_sizes; (void)n_in; (void)out_size; (void)ws_size;
    const float* x      = (const float*)d_in[0];
    const float* n1g    = (const float*)d_in[1];
    const float* n1b    = (const float*)d_in[2];
    const float* qkv_w  = (const float*)d_in[3];
    const float* qkv_b  = (const float*)d_in[4];
    const float* proj_w = (const float*)d_in[5];
    const float* proj_b = (const float*)d_in[6];
    const float* rpb    = (const float*)d_in[7];
    const float* n2g    = (const float*)d_in[8];
    const float* n2b    = (const float*)d_in[9];
    const float* w1     = (const float*)d_in[10];
    const float* b1     = (const float*)d_in[11];
    const float* w2     = (const float*)d_in[12];
    const float* b2     = (const float*)d_in[13];

    const size_t R384 = (size_t)TOKENS * CDIM;      // 38,535,168

    f16*   xn   = (f16*)d_ws;                       // [TOKENS*384]
    f16*   scr  = xn + R384;                        // [MCHUNK*1536] scratch
    f16*   qkvc = scr;                              // qkv chunk  [MCHUNK*1152]
    f16*   hbuf = scr;                              // mlp hidden [MCHUNK*1536]
    f16*   ao   = scr + (size_t)MCHUNK * MLPDIM;    // [TOKENS*384]
    f16*   wq   = ao + R384;                        // weights (fp16, [N][K])
    f16*   wp   = wq + (size_t)CDIM * QKVDIM;
    f16*   w1t  = wp + (size_t)CDIM * CDIM;
    f16*   w2t  = w1t + (size_t)CDIM * MLPDIM;
    float* x2   = (float*)d_out;                    // post-attn residual

    // weight transpose + fp16 convert (every call; ws re-poisoned by harness)
    wsplit_k<<<dim3(CDIM / 32, QKVDIM / 32), 256, 0, stream>>>(qkv_w, wq, CDIM, QKVDIM);
    wsplit_k<<<dim3(CDIM / 32, CDIM / 32), 256, 0, stream>>>(proj_w, wp, CDIM, CDIM);
    wsplit_k<<<dim3(CDIM / 32, MLPDIM / 32), 256, 0, stream>>>(w1, w1t, CDIM, MLPDIM);
    wsplit_k<<<dim3(MLPDIM / 32, CDIM / 32), 256, 0, stream>>>(w2, w2t, MLPDIM, CDIM);

    // LN1 (token->window gather) over all tokens
    ln_k<1><<<TOKENS / 4, 256, 0, stream>>>(x, n1g, n1b, xn);

    // qkv GEMM + attention, chunked (qkv never fully resident)
    for (int c = 0; c < NCHUNK; ++c) {
        const size_t ro = (size_t)c * MCHUNK;
        bgemm_k<0><<<dim3(MCHUNK / 128, QKVDIM / 128), 256, 0, stream>>>(
            xn + ro * CDIM, wq, qkv_b, nullptr, nullptr, qkvc, QKVDIM, CDIM);
        attn_k<<<dim3(WCHUNK, 12), 256, 0, stream>>>(
            qkvc, rpb, ao, c * WCHUNK);
    }

    // proj GEMM: window order -> token order scatter, +skip(x), into d_out
    bgemm_k<1><<<dim3(TOKENS / 128, CDIM / 128), 256, 0, stream>>>(
        ao, wp, proj_b, x, x2, nullptr, CDIM, CDIM);

    // LN2 (token order, source d_out)
    ln_k<0><<<TOKENS / 4, 256, 0, stream>>>(x2, n2g, n2b, xn);

    // MLP, chunked (hidden never fully resident); mlp2 in-place on d_out
    for (int c = 0; c < NCHUNK; ++c) {
        const size_t ro = (size_t)c * MCHUNK;
        bgemm_k<2><<<dim3(MCHUNK / 128, MLPDIM / 128), 256, 0, stream>>>(
            xn + ro * CDIM, w1t, b1, nullptr, nullptr, hbuf, MLPDIM, CDIM);
        bgemm_k<3><<<dim3(MCHUNK / 128, CDIM / 128), 256, 0, stream>>>(
            hbuf, w2t, b2, x2 + ro * CDIM, x2 + ro * CDIM, nullptr,
            CDIM, MLPDIM);
    }
}